// Round 11
// baseline (277.821 us; speedup 1.0000x reference)
//
#include <hip/hip_runtime.h>
#include <hip/hip_bf16.h>
#include <math.h>

#define B_     128
#define DIM_   512
#define HEADS_ 8
#define HD_    64
#define N_     196
#define NP_    224            // padded n (14 tiles of 16)
#define NROW_  208            // padded n rows (13 tiles of 16) for EB
#define SCALE_ 0.125f
#define BSTRIDE (DIM_ * N_)
#define J_     (B_ * NP_)     // 28672 GEMM columns (b*224+n)

typedef unsigned short u16;
typedef unsigned int   u32;
typedef __attribute__((ext_vector_type(8))) short bf16x8;   // 8 bf16 = 4 VGPRs
typedef __attribute__((ext_vector_type(4))) float f32x4;

__device__ __forceinline__ u16 f2bf(float f) {              // RNE fp32->bf16
    u32 u = __float_as_uint(f);
    return (u16)((u + 0x7fffu + ((u >> 16) & 1u)) >> 16);
}
__device__ __forceinline__ void gload_lds16(const u16* g, u16* l) {
    // async global->LDS, 16B/lane; LDS dest = wave-uniform base + lane*16
    __builtin_amdgcn_global_load_lds(
        (const __attribute__((address_space(1))) void*)g,
        (__attribute__((address_space(3))) void*)l, 16, 0, 0);
}

// ---------------------------------------------------------------------------
// Frag-major layout (r11, verified): FM[row/16][k/32][quad][m16][8 bf16].
// u16 addr(row,k) = (row>>4)*8192 + (k>>5)*512 + ((k>>3)&3)*128 + (row&15)*8
//                 + (k&7)        [K=512 fixed -> 16 kt slots]
// One MFMA fragment (16 rows x 8 k for 64 lanes) = 1 KB CONTIGUOUS.
// ---------------------------------------------------------------------------

// ---------------------------------------------------------------------------
// FUSED prep kernel (r15, verified; saved ~2 launch gaps).
//   blocks [0,4096)            : cvt_xT  (ct=id&7, ntb=(id>>3)&3, b=id>>5)
//   blocks [4096,5760)         : mk_eb   (e: n=e%208, h=e/208)
//   blocks [5760,6144)         : cvt_w2 qkv  (chunk block 0..383)
//   blocks [6144,6272)         : cvt_w2 proj (chunk block 0..127)
// ---------------------------------------------------------------------------
__global__ __launch_bounds__(256) void prep(
    const float* __restrict__ x, u16* __restrict__ XT,
    const float* __restrict__ qw, u16* __restrict__ qd,
    const float* __restrict__ pw, u16* __restrict__ pd,
    const float* __restrict__ biases, const int* __restrict__ bidx,
    float* __restrict__ EB)
{
    const int id = blockIdx.x;
    const int t = threadIdx.x;
    if (id < 4096) {                     // ---- cvt_xT ----
        __shared__ float tile[64][65];
        const int jj = t & 63, ii = t >> 6;
        const int ct = id & 7, ntb = (id >> 3) & 3, b = id >> 5;
        const float* xb = x + ((size_t)b * DIM_ + ct * 64) * N_;
        const int n0 = ntb * 64;
        #pragma unroll
        for (int s = 0; s < 16; ++s) {
            const int i = ii + s * 4;
            const int n = n0 + jj;
            tile[i][jj] = (n < N_) ? xb[(size_t)i * N_ + n] : 0.f;
        }
        __syncthreads();
        const int lo = t & 15, hi = t >> 4;
        const int c8 = hi & 7, ng = hi >> 3;
        #pragma unroll
        for (int s = 0; s < 2; ++s) {
            const int n_loc = (s * 2 + ng) * 16 + lo;
            const int nn = n0 + n_loc;
            if (nn < N_) {
                const int j = b * NP_ + nn;        // j&15 == lo
                const int c0 = ct * 64 + c8 * 8;
                u16 vv[8];
                #pragma unroll
                for (int e = 0; e < 8; ++e) vv[e] = f2bf(tile[c8 * 8 + e][n_loc]);
                uint4 o;
                o.x = (u32)vv[0] | ((u32)vv[1] << 16);
                o.y = (u32)vv[2] | ((u32)vv[3] << 16);
                o.z = (u32)vv[4] | ((u32)vv[5] << 16);
                o.w = (u32)vv[6] | ((u32)vv[7] << 16);
                *reinterpret_cast<uint4*>(XT + (size_t)(j >> 4) * 8192
                    + (c0 >> 5) * 512 + ((c0 >> 3) & 3) * 128 + (j & 15) * 8) = o;
            }
        }
    } else if (id < 5760) {              // ---- mk_eb ----
        const int e = id - 4096;
        const int n = e % NROW_, h = e / NROW_;
        const int m = t;
        if (m < NP_) {
            float v = 0.f;
            if (n < N_ && m < N_) v = __expf(biases[h * N_ + bidx[n * N_ + m]]);
            EB[((size_t)h * NROW_ + n) * NP_ + m] = v;
        }
    } else {                             // ---- cvt_w2 ----
        const bool pj = id >= 6144;
        const int cb = id - (pj ? 6144 : 5760);
        const float* src = pj ? pw : qw;
        u16* dst = pj ? pd : qd;
        const int nch = pj ? (DIM_ * DIM_ / 8) : (3 * DIM_ * DIM_ / 8);
        const int c = cb * 256 + t;
        if (c < nch) {
            const int m16 = c & 15, q = (c >> 4) & 3, kb = (c >> 6) & 15, mb = c >> 10;
            const float* s = src + (size_t)(mb * 16 + m16) * DIM_ + kb * 32 + q * 8;
            const float4 v0 = reinterpret_cast<const float4*>(s)[0];
            const float4 v1 = reinterpret_cast<const float4*>(s)[1];
            uint4 o;
            o.x = (u32)f2bf(v0.x) | ((u32)f2bf(v0.y) << 16);
            o.y = (u32)f2bf(v0.z) | ((u32)f2bf(v0.w) << 16);
            o.z = (u32)f2bf(v1.x) | ((u32)f2bf(v1.y) << 16);
            o.w = (u32)f2bf(v1.z) | ((u32)f2bf(v1.w) << 16);
            reinterpret_cast<uint4*>(dst)[c] = o;
        }
    }
}

// ---------------------------------------------------------------------------
// r16 GEMM: B-only LDS staging + register-direct A. Why: six structures
// (r8/r9/r11/r12/r14/r15) pin at ~78us; LDS-pipe arithmetic finally explains
// it -- per CU 10.5 blocks x (256 KB stage-write + 512 KB frag-read) = 8.1 MB
// at ~85-100 B/cyc (m134) = ~34us, and FLOP/LDS-byte x 85 B/cyc ~= MFMA peak:
// the LDS pipe is co-saturated, so every LDS-staged 2-phase variant lands on
// the same number (r11's all-register variant moved the same bytes via L1 ->
// same wall). r14 showed register-direct A works; it failed on grid
// starvation (224 blocks / 256 CU). Fix: keep r15's PROVEN 2-phase BK=64
// dbuf sync + grid + swizzle + epilogue byte-for-byte, but stage ONLY B
// (4 gload_lds/thread/kt, LDS 32 KB/block, traffic halved to 384 KB/block);
// A-frags load straight to VGPR from frag-major W (8 coalesced 16B frag
// loads/kt, r11-verified mapping; W = 1.5 MB, L2-resident, mt-fastest
// swizzle keeps it XCD-local). A-loads issue BEFORE the B-prefetch so
// counted vmcnt retires them (FIFO oldest-first) without draining the
// prefetch. Occupancy: LDS allows 5 blocks/CU, VGPR (~64 acc + 48 operand)
// ~3 -> 12 waves/CU vs 8.
// XCD swizzle (verified r8: FETCH 87->34MB): mt-fastest, bijective, NWG%8==0.
// Epilogue QKV: qT/kT[b][h][n<=224][64] (8B stores), vS[b][h][d][224];
// pads stored unguarded -- EB=0 masks every pad contribution downstream.
// Epilogue proj: fp32 out[b][512][196], n guarded.
// ---------------------------------------------------------------------------
template<bool QKV>
__global__ __launch_bounds__(256) void gemmF(
    const u16* __restrict__ Bt, const u16* __restrict__ W,
    const float* __restrict__ bias,
    u16* __restrict__ o_q, u16* __restrict__ o_k, u16* __restrict__ o_v,
    float* __restrict__ o_f)
{
    __shared__ u16 Bs[2][8192];         // 2 x 16 KB (128 rows x 64 k, frag-major)
    const int t = threadIdx.x;
    const int wave = t >> 6, lane = t & 63;
    const int m16 = lane & 15, quad = lane >> 4;

    constexpr int MT  = QKV ? 12 : 4;
    constexpr int NWG = (J_ / 128) * MT;
    const int bid = blockIdx.x;
    const int swz = (bid & 7) * (NWG / 8) + (bid >> 3);   // bijective XCD swizzle
    const int mt = swz % MT;                               // mt fastest
    const int jt = swz / MT;
    const int m0 = mt * 128, j0 = jt * 128;
    const int wy = wave >> 1, wx = wave & 1;     // wave tile: rows wy*64, cols wx*64

    // B staging: per tile 16 KB = 1024 x 16B chunks, 4/thread. chunk g=c*256+t:
    // frag-row f=g>>7, slot s=(g>>6)&1, lane-chunk ch=g&63; dst LDS linear g*8
    // (wave-uniform base + lane*16B per call). src frag-major, contiguous.
    const u16* gBb = Bt + (size_t)(jt * 8) * 8192;
    // A register-direct: frag(fi, kt, s) at A2 + fi*8192 + (kt*2+s)*512
    const u16* A2 = W + (size_t)(mt * 8 + wy * 4) * 8192 + quad * 128 + m16 * 8;

    // frag read offset within a (frag-row, slot): quad*128 + m16*8
    const int roff = quad * 128 + m16 * 8;

    f32x4 acc[4][4];
    const f32x4 z4 = {0.f, 0.f, 0.f, 0.f};
    #pragma unroll
    for (int fi = 0; fi < 4; ++fi)
        #pragma unroll
        for (int fj = 0; fj < 4; ++fj) acc[fi][fj] = z4;

    // prologue: stage B tile 0 into buf 0
    #pragma unroll
    for (int c = 0; c < 4; ++c) {
        const int g = c * 256 + t;
        const int f = g >> 7, s = (g >> 6) & 1, ch = g & 63;
        gload_lds16(gBb + (size_t)f * 8192 + s * 512 + ch * 8, Bs[0] + g * 8);
    }
    for (int kt = 0; kt < 8; ++kt) {             // 8 K-tiles of 64
        const int cur = kt & 1;
        __syncthreads();      // vmcnt(0)+lgkmcnt(0) drain: B tile-kt staged &
                              // visible; all waves done reading buf[cur^1]
        // A-frags for both ks-slots of this kt: 8 coalesced 16B loads, issued
        // FIRST so they retire (FIFO) without draining the B-prefetch below.
        bf16x8 af[2][4];
        #pragma unroll
        for (int s = 0; s < 2; ++s)
            #pragma unroll
            for (int fi = 0; fi < 4; ++fi)
                af[s][fi] = *reinterpret_cast<const bf16x8*>(
                    A2 + (size_t)fi * 8192 + (kt * 2 + s) * 512);
        if (kt < 7) {         // prefetch B tile kt+1
            #pragma unroll
            for (int c = 0; c < 4; ++c) {
                const int g = c * 256 + t;
                const int f = g >> 7, s = (g >> 6) & 1, ch = g & 63;
                gload_lds16(gBb + (size_t)f * 8192 + ((kt + 1) * 2 + s) * 512 + ch * 8, Bs[cur ^ 1] + g * 8);
            }
        }
        #pragma unroll
        for (int ks = 0; ks < 2; ++ks) {
            bf16x8 bf[4];
            #pragma unroll
            for (int fj = 0; fj < 4; ++fj)
                bf[fj] = *reinterpret_cast<const bf16x8*>(Bs[cur] + ((wx * 4 + fj) * 2 + ks) * 512 + roff);
            #pragma unroll
            for (int fi = 0; fi < 4; ++fi)
                #pragma unroll
                for (int fj = 0; fj < 4; ++fj)
                    acc[fi][fj] = __builtin_amdgcn_mfma_f32_16x16x32_bf16(af[ks][fi], bf[fj], acc[fi][fj], 0, 0, 0);
        }
    }

    // ---- epilogue (r11-verified) ----
    const int mbase = m0 + wy * 64;              // 64-aligned -> part,h wave-uniform
    float bb[4][4];
    #pragma unroll
    for (int fi = 0; fi < 4; ++fi)
        #pragma unroll
        for (int r = 0; r < 4; ++r) bb[fi][r] = bias[mbase + fi * 16 + quad * 4 + r];

    if (QKV) {
        const int part = mbase >> 9;             // 0=q 1=k 2=v
        const int h = (mbase & 511) >> 6;
        #pragma unroll
        for (int fj = 0; fj < 4; ++fj) {
            const int j = j0 + wx * 64 + fj * 16 + m16;
            const u32 b = (u32)j / 224u;
            const int n = j - (int)b * 224;
            if (part < 2) {                      // q,k -> [b][h][n][64], 8B packed
                u16* base = (part == 0 ? o_q : o_k) + (((size_t)b * HEADS_ + h) * NP_ + n) * HD_;
                #pragma unroll
                for (int fi = 0; fi < 4; ++fi) {
                    const int d0 = fi * 16 + quad * 4;
                    uint2 pk;
                    pk.x = (u32)f2bf(acc[fi][fj][0] + bb[fi][0]) | ((u32)f2bf(acc[fi][fj][1] + bb[fi][1]) << 16);
                    pk.y = (u32)f2bf(acc[fi][fj][2] + bb[fi][2]) | ((u32)f2bf(acc[fi][fj][3] + bb[fi][3]) << 16);
                    *reinterpret_cast<uint2*>(base + d0) = pk;
                }
            } else {                             // v -> [b][h][d][224], 2B stores
                u16* vb = o_v + (((size_t)b * HEADS_ + h) * HD_) * NP_ + n;
                #pragma unroll
                for (int fi = 0; fi < 4; ++fi) {
                    const int d0 = fi * 16 + quad * 4;
                    #pragma unroll
                    for (int r = 0; r < 4; ++r)
                        vb[(size_t)(d0 + r) * NP_] = f2bf(acc[fi][fj][r] + bb[fi][r]);
                }
            }
        }
    } else {                                     // proj: fp32 out[b][512][196]
        #pragma unroll
        for (int fj = 0; fj < 4; ++fj) {
            const int j = j0 + wx * 64 + fj * 16 + m16;
            const u32 b = (u32)j / 224u;
            const int n = j - (int)b * 224;
            if (n < N_) {
                float* ob = o_f + (size_t)b * BSTRIDE + n;
                #pragma unroll
                for (int fi = 0; fi < 4; ++fi) {
                    const int r0 = mbase + fi * 16 + quad * 4;
                    #pragma unroll
                    for (int r = 0; r < 4; ++r)
                        ob[(size_t)(r0 + r) * N_] = acc[fi][fj][r] + bb[fi][r];
                }
            }
        }
    }
}

// ---------------------------------------------------------------------------
// MFMA attention per (b,h), 8 waves (512 thr). K and V staged in LDS once
// per block (verified r6 structure; r11: OT store frag-major, verified).
//   Ks[224][64] u16, chunk-XOR swizzled; Vs[64][232] row-padded;
//   P[8][16*232] per-wave. LDS 117.8 KB -> 1 block/CU.
// mx over all 14 mtiles incl. pads, EB=0 masks pad m; OT stores guarded n<196.
// ---------------------------------------------------------------------------
__global__ __launch_bounds__(512) void attn_mfma(
    const u16* __restrict__ qT, const u16* __restrict__ kT,
    const u16* __restrict__ vS, const float* __restrict__ EB,
    u16* __restrict__ OT)
{
    __shared__ u16 Ks[224 * 64];        // 28.7 KB, chunk-XOR swizzled
    __shared__ u16 Vs[64 * 232];        // 29.7 KB, row-padded
    __shared__ u16 P[8][16 * 232];      // 59.4 KB
    const int t = threadIdx.x;
    const int wave = t >> 6, lane = t & 63;
    const int m16 = lane & 15, quad = lane >> 4;
    const int b = blockIdx.x, h = blockIdx.y;
    const u16* qTb = qT + ((size_t)b * HEADS_ + h) * (NP_ * HD_);
    const u16* kTb = kT + ((size_t)b * HEADS_ + h) * (NP_ * HD_);
    const u16* vb  = vS + ((size_t)b * HEADS_ + h) * (HD_ * NP_);
    const float* ebh = EB + (size_t)h * NROW_ * NP_;
    u16* Pw = P[wave];
    const f32x4 z4 = {0.f, 0.f, 0.f, 0.f};

    // ---- stage K: 224 rows x 8 chunks(16B) = 1792 chunks over 512 thr ----
    #pragma unroll
    for (int i = 0; i < 4; ++i) {
        const int c = t + i * 512;
        if (c < 1792) {
            const int row = c >> 3, ch = c & 7;
            const bf16x8 d = *reinterpret_cast<const bf16x8*>(kTb + row * HD_ + ch * 8);
            *reinterpret_cast<bf16x8*>(Ks + row * 64 + ((ch ^ (row & 7)) * 8)) = d;
        }
    }
    // ---- stage V: 64 rows x 28 chunks(16B) = 1792 chunks, repack to 232 ----
    #pragma unroll
    for (int i = 0; i < 4; ++i) {
        const int c = t + i * 512;
        if (c < 1792) {
            const u32 row = (u32)c / 28u;
            const int ch = c - (int)row * 28;
            const bf16x8 d = *reinterpret_cast<const bf16x8*>(vb + (size_t)row * NP_ + ch * 8);
            *reinterpret_cast<bf16x8*>(Vs + row * 232 + ch * 8) = d;
        }
    }
    __syncthreads();

    for (int nt = wave; nt < 13; nt += 8) {
        f32x4 s[14];
        #pragma unroll
        for (int mt = 0; mt < 14; ++mt) s[mt] = z4;
        #pragma unroll
        for (int ks = 0; ks < 2; ++ks) {
            const bf16x8 a = *reinterpret_cast<const bf16x8*>(
                qTb + (size_t)(nt * 16 + m16) * HD_ + ks * 32 + quad * 8);
            const int ch = ((ks * 4 + quad) ^ (m16 & 7)) * 8;   // K swizzle inverse
            #pragma unroll
            for (int mtile = 0; mtile < 14; ++mtile) {
                const bf16x8 bf = *reinterpret_cast<const bf16x8*>(
                    Ks + (mtile * 16 + m16) * 64 + ch);
                s[mtile] = __builtin_amdgcn_mfma_f32_16x16x32_bf16(a, bf, s[mtile], 0, 0, 0);
            }
        }
        float mx[4] = {-INFINITY, -INFINITY, -INFINITY, -INFINITY};
        #pragma unroll
        for (int mt = 0; mt < 14; ++mt)
            #pragma unroll
            for (int r = 0; r < 4; ++r) mx[r] = fmaxf(mx[r], s[mt][r]);
        #pragma unroll
        for (int off = 1; off < 16; off <<= 1)
            #pragma unroll
            for (int r = 0; r < 4; ++r) mx[r] = fmaxf(mx[r], __shfl_xor(mx[r], off, 64));
        #pragma unroll
        for (int r = 0; r < 4; ++r) mx[r] *= SCALE_;

        const float* ebn = ebh + (size_t)(nt * 16 + quad * 4) * NP_ + m16;
        float sum[4] = {0.f, 0.f, 0.f, 0.f};
        #pragma unroll
        for (int mt = 0; mt < 14; ++mt) {
            #pragma unroll
            for (int r = 0; r < 4; ++r) {
                const float e = __expf(fmaf(s[mt][r], SCALE_, -mx[r])) * ebn[(size_t)r * NP_ + mt * 16];
                s[mt][r] = e;
                sum[r] += e;
            }
        }
        #pragma unroll
        for (int off = 1; off < 16; off <<= 1)
            #pragma unroll
            for (int r = 0; r < 4; ++r) sum[r] += __shfl_xor(sum[r], off, 64);
        float inv[4];
        #pragma unroll
        for (int r = 0; r < 4; ++r) inv[r] = 1.f / sum[r];

        #pragma unroll
        for (int mt = 0; mt < 14; ++mt)
            #pragma unroll
            for (int r = 0; r < 4; ++r)
                Pw[(quad * 4 + r) * 232 + mt * 16 + m16] = f2bf(s[mt][r] * inv[r]);

        f32x4 o[4];
        #pragma unroll
        for (int dt = 0; dt < 4; ++dt) o[dt] = z4;
        #pragma unroll
        for (int ks = 0; ks < 7; ++ks) {
            const bf16x8 a = *reinterpret_cast<const bf16x8*>(Pw + m16 * 232 + ks * 32 + quad * 8);
            #pragma unroll
            for (int dt = 0; dt < 4; ++dt) {
                const bf16x8 bf = *reinterpret_cast<const bf16x8*>(
                    Vs + (dt * 16 + m16) * 232 + ks * 32 + quad * 8);
                o[dt] = __builtin_amdgcn_mfma_f32_16x16x32_bf16(a, bf, o[dt], 0, 0, 0);
            }
        }
        #pragma unroll
        for (int r = 0; r < 4; ++r) {
            const int n = nt * 16 + quad * 4 + r;
            if (n < N_) {
                const int j = b * NP_ + n;
                #pragma unroll
                for (int dt = 0; dt < 4; ++dt) {
                    const int c = h * HD_ + dt * 16 + m16;
                    OT[(size_t)(j >> 4) * 8192 + (c >> 5) * 512
                       + ((c >> 3) & 3) * 128 + (j & 15) * 8 + (c & 7)] = f2bf(o[dt][r]);
                }
            }
        }
    }
}

extern "C" void kernel_launch(void* const* d_in, const int* in_sizes, int n_in,
                              void* d_out, int out_size, void* d_ws, size_t ws_size,
                              hipStream_t stream) {
    const float* x      = (const float*)d_in[0];
    const float* qkv_w  = (const float*)d_in[1];
    const float* qkv_b  = (const float*)d_in[2];
    const float* proj_w = (const float*)d_in[3];
    const float* proj_b = (const float*)d_in[4];
    const float* biases = (const float*)d_in[5];
    const int*   bidx   = (const int*)d_in[6];
    float* out = (float*)d_out;

    // ws layout (~92 MB; 103 MB proven safe):
    char* w = (char*)d_ws;
    u16* XT  = (u16*)w; w += (size_t)B_ * NP_ * DIM_ * 2;            // 29.4 MB frag-major (reused as OT)
    u16* qTw = (u16*)w; w += (size_t)B_ * HEADS_ * NP_ * HD_ * 2;    // 29.4 MB
    u16* vSw = (u16*)w; w += (size_t)B_ * HEADS_ * HD_ * NP_ * 2;    // 29.4 MB
    float* EB = (float*)w; w += (size_t)HEADS_ * NROW_ * NP_ * 4;    // 1.5 MB
    u16* wq  = (u16*)w; w += (size_t)3 * DIM_ * DIM_ * 2;            // 1.6 MB frag-major
    u16* wpj = (u16*)w;                                              // 0.5 MB frag-major
    u16* kTw = (u16*)d_out;                                          // kT parked in d_out

    prep<<<dim3(6272), 256, 0, stream>>>(x, XT, qkv_w, wq, proj_w, wpj, biases, bidx, EB);
    gemmF<true><<<dim3((J_ / 128) * 12), 256, 0, stream>>>(XT, wq, qkv_b, qTw, kTw, vSw, nullptr);
    attn_mfma<<<dim3(B_, HEADS_), 512, 0, stream>>>(qTw, kTw, vSw, EB, XT);
    gemmF<false><<<dim3((J_ / 128) * 4), 256, 0, stream>>>(XT, wpj, proj_b, nullptr, nullptr, nullptr, out);
}

// Round 13
// 258.086 us; speedup vs baseline: 1.0765x; 1.0765x over previous
//
#include <hip/hip_runtime.h>
#include <hip/hip_bf16.h>
#include <math.h>

#define B_     128
#define DIM_   512
#define HEADS_ 8
#define HD_    64
#define N_     196
#define NP_    224            // padded n (14 tiles of 16)
#define NROW_  208            // padded n rows (13 tiles of 16) for EB
#define SCALE_ 0.125f
#define BSTRIDE (DIM_ * N_)
#define J_     (B_ * NP_)     // 28672 GEMM columns (b*224+n)

typedef unsigned short u16;
typedef unsigned int   u32;
typedef __attribute__((ext_vector_type(8))) short bf16x8;   // 8 bf16 = 4 VGPRs
typedef __attribute__((ext_vector_type(4))) float f32x4;

__device__ __forceinline__ u16 f2bf(float f) {              // RNE fp32->bf16
    u32 u = __float_as_uint(f);
    return (u16)((u + 0x7fffu + ((u >> 16) & 1u)) >> 16);
}
__device__ __forceinline__ void gload_lds16(const u16* g, u16* l) {
    // async global->LDS, 16B/lane; LDS dest = wave-uniform base + lane*16
    __builtin_amdgcn_global_load_lds(
        (const __attribute__((address_space(1))) void*)g,
        (__attribute__((address_space(3))) void*)l, 16, 0, 0);
}

// ---------------------------------------------------------------------------
// Frag-major layout (r11, verified): FM[row/16][k/32][quad][m16][8 bf16].
// u16 addr(row,k) = (row>>4)*8192 + (k>>5)*512 + ((k>>3)&3)*128 + (row&15)*8
//                 + (k&7)        [K=512 fixed -> 16 kt slots]
// One MFMA fragment (16 rows x 8 k for 64 lanes) = 1 KB CONTIGUOUS.
// ---------------------------------------------------------------------------

// ---------------------------------------------------------------------------
// FUSED prep kernel (r15, verified; saved ~2 launch gaps).
//   blocks [0,4096)            : cvt_xT  (ct=id&7, ntb=(id>>3)&3, b=id>>5)
//   blocks [4096,5760)         : mk_eb   (e: n=e%208, h=e/208)
//   blocks [5760,6144)         : cvt_w2 qkv  (chunk block 0..383)
//   blocks [6144,6272)         : cvt_w2 proj (chunk block 0..127)
// ---------------------------------------------------------------------------
__global__ __launch_bounds__(256) void prep(
    const float* __restrict__ x, u16* __restrict__ XT,
    const float* __restrict__ qw, u16* __restrict__ qd,
    const float* __restrict__ pw, u16* __restrict__ pd,
    const float* __restrict__ biases, const int* __restrict__ bidx,
    float* __restrict__ EB)
{
    const int id = blockIdx.x;
    const int t = threadIdx.x;
    if (id < 4096) {                     // ---- cvt_xT ----
        __shared__ float tile[64][65];
        const int jj = t & 63, ii = t >> 6;
        const int ct = id & 7, ntb = (id >> 3) & 3, b = id >> 5;
        const float* xb = x + ((size_t)b * DIM_ + ct * 64) * N_;
        const int n0 = ntb * 64;
        #pragma unroll
        for (int s = 0; s < 16; ++s) {
            const int i = ii + s * 4;
            const int n = n0 + jj;
            tile[i][jj] = (n < N_) ? xb[(size_t)i * N_ + n] : 0.f;
        }
        __syncthreads();
        const int lo = t & 15, hi = t >> 4;
        const int c8 = hi & 7, ng = hi >> 3;
        #pragma unroll
        for (int s = 0; s < 2; ++s) {
            const int n_loc = (s * 2 + ng) * 16 + lo;
            const int nn = n0 + n_loc;
            if (nn < N_) {
                const int j = b * NP_ + nn;        // j&15 == lo
                const int c0 = ct * 64 + c8 * 8;
                u16 vv[8];
                #pragma unroll
                for (int e = 0; e < 8; ++e) vv[e] = f2bf(tile[c8 * 8 + e][n_loc]);
                uint4 o;
                o.x = (u32)vv[0] | ((u32)vv[1] << 16);
                o.y = (u32)vv[2] | ((u32)vv[3] << 16);
                o.z = (u32)vv[4] | ((u32)vv[5] << 16);
                o.w = (u32)vv[6] | ((u32)vv[7] << 16);
                *reinterpret_cast<uint4*>(XT + (size_t)(j >> 4) * 8192
                    + (c0 >> 5) * 512 + ((c0 >> 3) & 3) * 128 + (j & 15) * 8) = o;
            }
        }
    } else if (id < 5760) {              // ---- mk_eb ----
        const int e = id - 4096;
        const int n = e % NROW_, h = e / NROW_;
        const int m = t;
        if (m < NP_) {
            float v = 0.f;
            if (n < N_ && m < N_) v = __expf(biases[h * N_ + bidx[n * N_ + m]]);
            EB[((size_t)h * NROW_ + n) * NP_ + m] = v;
        }
    } else {                             // ---- cvt_w2 ----
        const bool pj = id >= 6144;
        const int cb = id - (pj ? 6144 : 5760);
        const float* src = pj ? pw : qw;
        u16* dst = pj ? pd : qd;
        const int nch = pj ? (DIM_ * DIM_ / 8) : (3 * DIM_ * DIM_ / 8);
        const int c = cb * 256 + t;
        if (c < nch) {
            const int m16 = c & 15, q = (c >> 4) & 3, kb = (c >> 6) & 15, mb = c >> 10;
            const float* s = src + (size_t)(mb * 16 + m16) * DIM_ + kb * 32 + q * 8;
            const float4 v0 = reinterpret_cast<const float4*>(s)[0];
            const float4 v1 = reinterpret_cast<const float4*>(s)[1];
            uint4 o;
            o.x = (u32)f2bf(v0.x) | ((u32)f2bf(v0.y) << 16);
            o.y = (u32)f2bf(v0.z) | ((u32)f2bf(v0.w) << 16);
            o.z = (u32)f2bf(v1.x) | ((u32)f2bf(v1.y) << 16);
            o.w = (u32)f2bf(v1.z) | ((u32)f2bf(v1.w) << 16);
            reinterpret_cast<uint4*>(dst)[c] = o;
        }
    }
}

// ---------------------------------------------------------------------------
// r18 == r17 resubmit (container infra failure, no kernel verdict; hang
// audit: barriers wave-uniform & unconditional, vmcnt ledger consistent at
// every kt, STAGE dest wave-uniform + lane*16B, LDS 128KB < 160KB -> no
// deadlock possible; correctness risks would show as passed:false).
// Faithful m201-style 8-phase 256x256 port (T3+T4+T5). Seven 2-phase-family
// structures (r8/r9/r10/r11/r12/r14/r15/r16) all pinned at 78-122us = the
// m233 2-phase ceiling; per the catalog only the full 8-phase schedule
// breaks it (m248 same-probe: 2ph 655 -> 8ph-full 848).
// Geometry: 256x256 tile, 8 waves (wave=128x64, 8x4 frags, 128 VGPR acc),
// BK=64; LDS = 4 half-tile slots x 32 KB = 128 KB (half-tile h: ks-half h&1
// of K-tile h>>1; slot h&3; layout [A 8192 u16 | B 8192 u16], frag-major ->
// ds_read_b128 CONFLICT-FREE by construction (r14: 0 conflicts), replacing
// m201's st_16x32 swizzle).
// Schedule per kt (4 phases = m201's 4/K-tile cadence):
//  ph0: vmcnt(4)* ; barrier ; stage(half 2kt+2, part0) ; ds_read af[8]+bf0,1
//       (slot 2kt) ; lgkmcnt(0) ; setprio(1) 16 MFMA setprio(0) ; barrier
//  ph1: stage(part1) ; ds_read bf2,3 ; 16 MFMA   (af reused in regs)
//  ph2: vmcnt(4)* ; barrier ; stage(half 2kt+3, part0) ; ds_read ks=1 ; 16 MFMA ; barrier
//  ph3: stage(part1) ; ds_read bf2,3 ; 16 MFMA
//  (*kt=0: vmcnt(12)/vmcnt(8); kt=7: ph2 vmcnt(0); stages only for 1<=kt<=6;
//   prologue stages halves 0..3.)
// Race audit: RAW -- each wave's counted vmcnt retires ITS half-2kt loads
// (FIFO oldest-first, m135) before the barrier; barrier -> all waves' loads
// landed. WAR -- stage of half h overwrites slot of h-4, read in kt-1 and
// completed (lgkmcnt before that phase's MFMA) >=2 barriers before the
// issue; the async write lands after issue. Barriers wave-uniform (kt
// unrolled, guards uniform). vmcnt counts only staging loads.
// XCD swizzle (verified r8): mt-fastest, bijective (672/224, %8==0).
// Epilogue = r11-verified per-64-row-group code; mbase=mt*256+wy*128+g*64
// (64-aligned -> part,h wave-uniform). QKV: qT/kT[b][h][n][64] 8B stores,
// vS[b][h][d][224] 2B; pads unguarded (EB=0 masks). proj: fp32 out, n<196.
// ---------------------------------------------------------------------------
template<bool QKV>
__global__ __launch_bounds__(512) void gemm8(
    const u16* __restrict__ Bt, const u16* __restrict__ W,
    const float* __restrict__ bias,
    u16* __restrict__ o_q, u16* __restrict__ o_k, u16* __restrict__ o_v,
    float* __restrict__ o_f)
{
    __shared__ u16 S[4 * 16384];        // 128 KB = 4 half-tile slots
    const int t = threadIdx.x;
    const int wave = t >> 6, lane = t & 63;
    const int m16 = lane & 15, quad = lane >> 4;

    constexpr int MT  = QKV ? 6 : 2;
    constexpr int NWG = (J_ / 256) * MT;
    const int bid = blockIdx.x;
    const int swz = (bid & 7) * (NWG / 8) + (bid >> 3);   // bijective XCD swizzle
    const int mt = swz % MT;                               // mt fastest
    const int jt = swz / MT;
    const int j0 = jt * 256;
    const int wy = wave >> 2, wx = wave & 3;   // wave tile: rows wy*128, cols wx*64

    const u16* gA = W  + (size_t)(mt * 16) * 8192;   // 16 frag-rows (256 rows)
    const u16* gB = Bt + (size_t)(jt * 16) * 8192;
    const int roff = quad * 128 + m16 * 8;

    // stage one part (2 chunks/thread) of half-tile h into slot h&3.
    // chunk g = t + 512*(part*2+i): g<1024 -> A frag-row g>>6, else B.
    // wave's 64 chunks are one contiguous 1KB frag in src AND dst (g lane-
    // linear, 1024%64==0 -> no A/B straddle).
    auto STAGE = [&](int h, int part) {
        const int s = h & 1, ktt = h >> 1, slot = h & 3;
        #pragma unroll
        for (int i = 0; i < 2; ++i) {
            const int g = t + 512 * (part * 2 + i);
            const int isB = g >> 10;
            const int fr = (g & 1023) >> 6, c = g & 63;
            const u16* src = (isB ? gB : gA) + (size_t)fr * 8192 + (ktt * 2 + s) * 512 + c * 8;
            gload_lds16(src, S + slot * 16384 + isB * 8192 + (g & 1023) * 8);
        }
    };

    f32x4 acc[8][4];
    const f32x4 z4 = {0.f, 0.f, 0.f, 0.f};
    #pragma unroll
    for (int fi = 0; fi < 8; ++fi)
        #pragma unroll
        for (int fj = 0; fj < 4; ++fj) acc[fi][fj] = z4;

    // prologue: stage halves 0..3 (16 loads/thread outstanding)
    #pragma unroll
    for (int h = 0; h < 4; ++h) { STAGE(h, 0); STAGE(h, 1); }

    #pragma unroll
    for (int kt = 0; kt < 8; ++kt) {
        const int sA = (2 * kt) & 3, sB = (2 * kt + 1) & 3;
        const bool doStage = (kt >= 1 && kt <= 6);
        // ================= ks = 0 (slot sA) =================
        if (kt == 0) asm volatile("s_waitcnt vmcnt(12)" ::: "memory");
        else         asm volatile("s_waitcnt vmcnt(4)"  ::: "memory");
        __builtin_amdgcn_s_barrier();
        if (doStage) STAGE(2 * kt + 2, 0);
        {
            bf16x8 af[8];
            #pragma unroll
            for (int fi = 0; fi < 8; ++fi)
                af[fi] = *reinterpret_cast<const bf16x8*>(S + sA * 16384 + (wy * 8 + fi) * 512 + roff);
            bf16x8 b0 = *reinterpret_cast<const bf16x8*>(S + sA * 16384 + 8192 + (wx * 4 + 0) * 512 + roff);
            bf16x8 b1 = *reinterpret_cast<const bf16x8*>(S + sA * 16384 + 8192 + (wx * 4 + 1) * 512 + roff);
            asm volatile("s_waitcnt lgkmcnt(0)" ::: "memory");
            __builtin_amdgcn_s_setprio(1);
            #pragma unroll
            for (int fi = 0; fi < 8; ++fi) {
                acc[fi][0] = __builtin_amdgcn_mfma_f32_16x16x32_bf16(af[fi], b0, acc[fi][0], 0, 0, 0);
                acc[fi][1] = __builtin_amdgcn_mfma_f32_16x16x32_bf16(af[fi], b1, acc[fi][1], 0, 0, 0);
            }
            __builtin_amdgcn_s_setprio(0);
            __builtin_amdgcn_s_barrier();
            // ---- ph1 ----
            if (doStage) STAGE(2 * kt + 2, 1);
            bf16x8 b2 = *reinterpret_cast<const bf16x8*>(S + sA * 16384 + 8192 + (wx * 4 + 2) * 512 + roff);
            bf16x8 b3 = *reinterpret_cast<const bf16x8*>(S + sA * 16384 + 8192 + (wx * 4 + 3) * 512 + roff);
            asm volatile("s_waitcnt lgkmcnt(0)" ::: "memory");
            __builtin_amdgcn_s_setprio(1);
            #pragma unroll
            for (int fi = 0; fi < 8; ++fi) {
                acc[fi][2] = __builtin_amdgcn_mfma_f32_16x16x32_bf16(af[fi], b2, acc[fi][2], 0, 0, 0);
                acc[fi][3] = __builtin_amdgcn_mfma_f32_16x16x32_bf16(af[fi], b3, acc[fi][3], 0, 0, 0);
            }
            __builtin_amdgcn_s_setprio(0);
        }
        // ================= ks = 1 (slot sB) =================
        if (kt == 0)      asm volatile("s_waitcnt vmcnt(8)" ::: "memory");
        else if (kt == 7) asm volatile("s_waitcnt vmcnt(0)" ::: "memory");
        else              asm volatile("s_waitcnt vmcnt(4)" ::: "memory");
        __builtin_amdgcn_s_barrier();
        if (doStage) STAGE(2 * kt + 3, 0);
        {
            bf16x8 af[8];
            #pragma unroll
            for (int fi = 0; fi < 8; ++fi)
                af[fi] = *reinterpret_cast<const bf16x8*>(S + sB * 16384 + (wy * 8 + fi) * 512 + roff);
            bf16x8 b0 = *reinterpret_cast<const bf16x8*>(S + sB * 16384 + 8192 + (wx * 4 + 0) * 512 + roff);
            bf16x8 b1 = *reinterpret_cast<const bf16x8*>(S + sB * 16384 + 8192 + (wx * 4 + 1) * 512 + roff);
            asm volatile("s_waitcnt lgkmcnt(0)" ::: "memory");
            __builtin_amdgcn_s_setprio(1);
            #pragma unroll
            for (int fi = 0; fi < 8; ++fi) {
                acc[fi][0] = __builtin_amdgcn_mfma_f32_16x16x32_bf16(af[fi], b0, acc[fi][0], 0, 0, 0);
                acc[fi][1] = __builtin_amdgcn_mfma_f32_16x16x32_bf16(af[fi], b1, acc[fi][1], 0, 0, 0);
            }
            __builtin_amdgcn_s_setprio(0);
            __builtin_amdgcn_s_barrier();
            // ---- ph3 ----
            if (doStage) STAGE(2 * kt + 3, 1);
            bf16x8 b2 = *reinterpret_cast<const bf16x8*>(S + sB * 16384 + 8192 + (wx * 4 + 2) * 512 + roff);
            bf16x8 b3 = *reinterpret_cast<const bf16x8*>(S + sB * 16384 + 8192 + (wx * 4 + 3) * 512 + roff);
            asm volatile("s_waitcnt lgkmcnt(0)" ::: "memory");
            __builtin_amdgcn_s_setprio(1);
            #pragma unroll
            for (int fi = 0; fi < 8; ++fi) {
                acc[fi][2] = __builtin_amdgcn_mfma_f32_16x16x32_bf16(af[fi], b2, acc[fi][2], 0, 0, 0);
                acc[fi][3] = __builtin_amdgcn_mfma_f32_16x16x32_bf16(af[fi], b3, acc[fi][3], 0, 0, 0);
            }
            __builtin_amdgcn_s_setprio(0);
        }
    }

    // ---- epilogue: two 64-row groups per wave (r11-verified math) ----
    #pragma unroll
    for (int g = 0; g < 2; ++g) {
        const int mbase = mt * 256 + wy * 128 + g * 64;   // 64-aligned -> uniform
        float bb[4][4];
        #pragma unroll
        for (int fi = 0; fi < 4; ++fi)
            #pragma unroll
            for (int r = 0; r < 4; ++r) bb[fi][r] = bias[mbase + fi * 16 + quad * 4 + r];

        if (QKV) {
            const int part = mbase >> 9;             // 0=q 1=k 2=v
            const int h = (mbase & 511) >> 6;
            #pragma unroll
            for (int fj = 0; fj < 4; ++fj) {
                const int j = j0 + wx * 64 + fj * 16 + m16;
                const u32 b = (u32)j / 224u;
                const int n = j - (int)b * 224;
                if (part < 2) {                      // q,k -> [b][h][n][64], 8B packed
                    u16* base = (part == 0 ? o_q : o_k) + (((size_t)b * HEADS_ + h) * NP_ + n) * HD_;
                    #pragma unroll
                    for (int fi = 0; fi < 4; ++fi) {
                        const int d0 = fi * 16 + quad * 4;
                        uint2 pk;
                        pk.x = (u32)f2bf(acc[g * 4 + fi][fj][0] + bb[fi][0]) | ((u32)f2bf(acc[g * 4 + fi][fj][1] + bb[fi][1]) << 16);
                        pk.y = (u32)f2bf(acc[g * 4 + fi][fj][2] + bb[fi][2]) | ((u32)f2bf(acc[g * 4 + fi][fj][3] + bb[fi][3]) << 16);
                        *reinterpret_cast<uint2*>(base + d0) = pk;
                    }
                } else {                             // v -> [b][h][d][224], 2B stores
                    u16* vb = o_v + (((size_t)b * HEADS_ + h) * HD_) * NP_ + n;
                    #pragma unroll
                    for (int fi = 0; fi < 4; ++fi) {
                        const int d0 = fi * 16 + quad * 4;
                        #pragma unroll
                        for (int r = 0; r < 4; ++r)
                            vb[(size_t)(d0 + r) * NP_] = f2bf(acc[g * 4 + fi][fj][r] + bb[fi][r]);
                    }
                }
            }
        } else {                                     // proj: fp32 out[b][512][196]
            #pragma unroll
            for (int fj = 0; fj < 4; ++fj) {
                const int j = j0 + wx * 64 + fj * 16 + m16;
                const u32 b = (u32)j / 224u;
                const int n = j - (int)b * 224;
                if (n < N_) {
                    float* ob = o_f + (size_t)b * BSTRIDE + n;
                    #pragma unroll
                    for (int fi = 0; fi < 4; ++fi) {
                        const int r0 = mbase + fi * 16 + quad * 4;
                        #pragma unroll
                        for (int r = 0; r < 4; ++r)
                            ob[(size_t)(r0 + r) * N_] = acc[g * 4 + fi][fj][r] + bb[fi][r];
                    }
                }
            }
        }
    }
}

// ---------------------------------------------------------------------------
// MFMA attention per (b,h), 8 waves (512 thr). K and V staged in LDS once
// per block (verified r6 structure; r11: OT store frag-major, verified).
//   Ks[224][64] u16, chunk-XOR swizzled; Vs[64][232] row-padded;
//   P[8][16*232] per-wave. LDS 117.8 KB -> 1 block/CU.
// mx over all 14 mtiles incl. pads, EB=0 masks pad m; OT stores guarded n<196.
// ---------------------------------------------------------------------------
__global__ __launch_bounds__(512) void attn_mfma(
    const u16* __restrict__ qT, const u16* __restrict__ kT,
    const u16* __restrict__ vS, const float* __restrict__ EB,
    u16* __restrict__ OT)
{
    __shared__ u16 Ks[224 * 64];        // 28.7 KB, chunk-XOR swizzled
    __shared__ u16 Vs[64 * 232];        // 29.7 KB, row-padded
    __shared__ u16 P[8][16 * 232];      // 59.4 KB
    const int t = threadIdx.x;
    const int wave = t >> 6, lane = t & 63;
    const int m16 = lane & 15, quad = lane >> 4;
    const int b = blockIdx.x, h = blockIdx.y;
    const u16* qTb = qT + ((size_t)b * HEADS_ + h) * (NP_ * HD_);
    const u16* kTb = kT + ((size_t)b * HEADS_ + h) * (NP_ * HD_);
    const u16* vb  = vS + ((size_t)b * HEADS_ + h) * (HD_ * NP_);
    const float* ebh = EB + (size_t)h * NROW_ * NP_;
    u16* Pw = P[wave];
    const f32x4 z4 = {0.f, 0.f, 0.f, 0.f};

    // ---- stage K: 224 rows x 8 chunks(16B) = 1792 chunks over 512 thr ----
    #pragma unroll
    for (int i = 0; i < 4; ++i) {
        const int c = t + i * 512;
        if (c < 1792) {
            const int row = c >> 3, ch = c & 7;
            const bf16x8 d = *reinterpret_cast<const bf16x8*>(kTb + row * HD_ + ch * 8);
            *reinterpret_cast<bf16x8*>(Ks + row * 64 + ((ch ^ (row & 7)) * 8)) = d;
        }
    }
    // ---- stage V: 64 rows x 28 chunks(16B) = 1792 chunks, repack to 232 ----
    #pragma unroll
    for (int i = 0; i < 4; ++i) {
        const int c = t + i * 512;
        if (c < 1792) {
            const u32 row = (u32)c / 28u;
            const int ch = c - (int)row * 28;
            const bf16x8 d = *reinterpret_cast<const bf16x8*>(vb + (size_t)row * NP_ + ch * 8);
            *reinterpret_cast<bf16x8*>(Vs + row * 232 + ch * 8) = d;
        }
    }
    __syncthreads();

    for (int nt = wave; nt < 13; nt += 8) {
        f32x4 s[14];
        #pragma unroll
        for (int mt = 0; mt < 14; ++mt) s[mt] = z4;
        #pragma unroll
        for (int ks = 0; ks < 2; ++ks) {
            const bf16x8 a = *reinterpret_cast<const bf16x8*>(
                qTb + (size_t)(nt * 16 + m16) * HD_ + ks * 32 + quad * 8);
            const int ch = ((ks * 4 + quad) ^ (m16 & 7)) * 8;   // K swizzle inverse
            #pragma unroll
            for (int mtile = 0; mtile < 14; ++mtile) {
                const bf16x8 bf = *reinterpret_cast<const bf16x8*>(
                    Ks + (mtile * 16 + m16) * 64 + ch);
                s[mtile] = __builtin_amdgcn_mfma_f32_16x16x32_bf16(a, bf, s[mtile], 0, 0, 0);
            }
        }
        float mx[4] = {-INFINITY, -INFINITY, -INFINITY, -INFINITY};
        #pragma unroll
        for (int mt = 0; mt < 14; ++mt)
            #pragma unroll
            for (int r = 0; r < 4; ++r) mx[r] = fmaxf(mx[r], s[mt][r]);
        #pragma unroll
        for (int off = 1; off < 16; off <<= 1)
            #pragma unroll
            for (int r = 0; r < 4; ++r) mx[r] = fmaxf(mx[r], __shfl_xor(mx[r], off, 64));
        #pragma unroll
        for (int r = 0; r < 4; ++r) mx[r] *= SCALE_;

        const float* ebn = ebh + (size_t)(nt * 16 + quad * 4) * NP_ + m16;
        float sum[4] = {0.f, 0.f, 0.f, 0.f};
        #pragma unroll
        for (int mt = 0; mt < 14; ++mt) {
            #pragma unroll
            for (int r = 0; r < 4; ++r) {
                const float e = __expf(fmaf(s[mt][r], SCALE_, -mx[r])) * ebn[(size_t)r * NP_ + mt * 16];
                s[mt][r] = e;
                sum[r] += e;
            }
        }
        #pragma unroll
        for (int off = 1; off < 16; off <<= 1)
            #pragma unroll
            for (int r = 0; r < 4; ++r) sum[r] += __shfl_xor(sum[r], off, 64);
        float inv[4];
        #pragma unroll
        for (int r = 0; r < 4; ++r) inv[r] = 1.f / sum[r];

        #pragma unroll
        for (int mt = 0; mt < 14; ++mt)
            #pragma unroll
            for (int r = 0; r < 4; ++r)
                Pw[(quad * 4 + r) * 232 + mt * 16 + m16] = f2bf(s[mt][r] * inv[r]);

        f32x4 o[4];
        #pragma unroll
        for (int dt = 0; dt < 4; ++dt) o[dt] = z4;
        #pragma unroll
        for (int ks = 0; ks < 7; ++ks) {
            const bf16x8 a = *reinterpret_cast<const bf16x8*>(Pw + m16 * 232 + ks * 32 + quad * 8);
            #pragma unroll
            for (int dt = 0; dt < 4; ++dt) {
                const bf16x8 bf = *reinterpret_cast<const bf16x8*>(
                    Vs + (dt * 16 + m16) * 232 + ks * 32 + quad * 8);
                o[dt] = __builtin_amdgcn_mfma_f32_16x16x32_bf16(a, bf, o[dt], 0, 0, 0);
            }
        }
        #pragma unroll
        for (int r = 0; r < 4; ++r) {
            const int n = nt * 16 + quad * 4 + r;
            if (n < N_) {
                const int j = b * NP_ + n;
                #pragma unroll
                for (int dt = 0; dt < 4; ++dt) {
                    const int c = h * HD_ + dt * 16 + m16;
                    OT[(size_t)(j >> 4) * 8192 + (c >> 5) * 512
                       + ((c >> 3) & 3) * 128 + (j & 15) * 8 + (c & 7)] = f2bf(o[dt][r]);
                }
            }
        }
    }
}

extern "C" void kernel_launch(void* const* d_in, const int* in_sizes, int n_in,
                              void* d_out, int out_size, void* d_ws, size_t ws_size,
                              hipStream_t stream) {
    const float* x      = (const float*)d_in[0];
    const float* qkv_w  = (const float*)d_in[1];
    const float* qkv_b  = (const float*)d_in[2];
    const float* proj_w = (const float*)d_in[3];
    const float* proj_b = (const float*)d_in[4];
    const float* biases = (const float*)d_in[5];
    const int*   bidx   = (const int*)d_in[6];
    float* out = (float*)d_out;

    // ws layout (~92 MB; 103 MB proven safe):
    char* w = (char*)d_ws;
    u16* XT  = (u16*)w; w += (size_t)B_ * NP_ * DIM_ * 2;            // 29.4 MB frag-major (reused as OT)
    u16* qTw = (u16*)w; w += (size_t)B_ * HEADS_ * NP_ * HD_ * 2;    // 29.4 MB
    u16* vSw = (u16*)w; w += (size_t)B_ * HEADS_ * HD_ * NP_ * 2;    // 29.4 MB
    float* EB = (float*)w; w += (size_t)HEADS_ * NROW_ * NP_ * 4;    // 1.5 MB
    u16* wq  = (u16*)w; w += (size_t)3 * DIM_ * DIM_ * 2;            // 1.6 MB frag-major
    u16* wpj = (u16*)w;                                              // 0.5 MB frag-major
    u16* kTw = (u16*)d_out;                                          // kT parked in d_out

    prep<<<dim3(6272), 256, 0, stream>>>(x, XT, qkv_w, wq, proj_w, wpj, biases, bidx, EB);
    gemm8<true><<<dim3((J_ / 256) * 6), 512, 0, stream>>>(XT, wq, qkv_b, qTw, kTw, vSw, nullptr);
    attn_mfma<<<dim3(B_, HEADS_), 512, 0, stream>>>(qTw, kTw, vSw, EB, XT);
    gemm8<false><<<dim3((J_ / 256) * 2), 512, 0, stream>>>(XT, wpj, proj_b, nullptr, nullptr, nullptr, out);
}